// Round 3
// baseline (109.192 us; speedup 1.0000x reference)
//
#include <hip/hip_runtime.h>
#include <hip/hip_bf16.h>

// out[8192,64] = L[8192,8192] (fp32) @ M[8192,64] (fp32)
// Kernel 1: BT[h][k] = (bf16)M[k][h]  (1 MB in d_ws, L2-resident)
// Kernel 2: barrier-free, LDS-free streaming MFMA. A: global->VGPR fragment
//           loads (reg double-buffered); B: direct 16-B fragment loads from BT.
// Split-K=8 with fp32 atomics onto memset-zeroed d_out.

#define NPED 8192
#define HID  64
#define BM   64
#define BK   64
#define KSPLIT 8
#define KRANGE (NPED / KSPLIT)   // 1024
#define NSTEPS (KRANGE / BK)     // 16

typedef __bf16 bf16x8 __attribute__((ext_vector_type(8)));
typedef float  f32x4  __attribute__((ext_vector_type(4)));
typedef unsigned short u16;
typedef u16 u16x8 __attribute__((ext_vector_type(8)));

__device__ __forceinline__ bf16x8 cvt8(float4 lo, float4 hi) {
    bf16x8 r;
    r[0] = (__bf16)lo.x; r[1] = (__bf16)lo.y; r[2] = (__bf16)lo.z; r[3] = (__bf16)lo.w;
    r[4] = (__bf16)hi.x; r[5] = (__bf16)hi.y; r[6] = (__bf16)hi.z; r[7] = (__bf16)hi.w;
    return r;
}

// ---- Kernel 1: B [8192,64] fp32 -> BT [64,8192] bf16 ----
__global__ __launch_bounds__(256)
void transpose_b(const float* __restrict__ B, u16* __restrict__ BT) {
    __shared__ u16 t[64][65];          // +1 pad
    const int tid = threadIdx.x;
    const int kb  = blockIdx.x * 64;   // 128 blocks cover k=0..8191

    {   // read 64 k-rows x 64 h, fully coalesced
        const int r  = tid >> 2;
        const int c0 = (tid & 3) * 16;
        const float* p = B + (long)(kb + r) * HID + c0;
        #pragma unroll
        for (int j = 0; j < 16; j += 4) {
            float4 v = *(const float4*)(p + j);
            __bf16 b0 = (__bf16)v.x, b1 = (__bf16)v.y, b2 = (__bf16)v.z, b3 = (__bf16)v.w;
            t[c0 + j + 0][r] = __builtin_bit_cast(u16, b0);
            t[c0 + j + 1][r] = __builtin_bit_cast(u16, b1);
            t[c0 + j + 2][r] = __builtin_bit_cast(u16, b2);
            t[c0 + j + 3][r] = __builtin_bit_cast(u16, b3);
        }
    }
    __syncthreads();
    {   // write 64 h-rows x 64 k, 32 B per thread
        const int h  = tid >> 2;
        const int kc = (tid & 3) * 16;
        u16x8 lo, hi;
        #pragma unroll
        for (int j = 0; j < 8; ++j) { lo[j] = t[h][kc + j]; hi[j] = t[h][kc + 8 + j]; }
        u16* q = BT + (long)h * NPED + kb + kc;
        *(u16x8*)(q)     = lo;
        *(u16x8*)(q + 8) = hi;
    }
}

// ---- Kernel 2: streaming MFMA, no LDS, no barriers ----
__global__ __launch_bounds__(256, 3)
void crowd_mm(const float* __restrict__ A, const u16* __restrict__ BT,
              float* __restrict__ out)
{
    const int tid  = threadIdx.x;
    const int lane = tid & 63;
    const int w    = tid >> 6;        // wave 0..3 owns rows w*16..+15
    const int rb   = blockIdx.x;
    const int ks   = blockIdx.y;
    const long kb  = (long)ks * KRANGE;

    const int l15 = lane & 15;
    const int l4  = lane >> 4;

    // A fragment: lane l -> row (l&15), k = (l>>4)*8 + [0..7]  (+32 for s=1)
    const float* Ap = A + (long)(rb * BM + w * 16 + l15) * NPED + kb + l4 * 8;
    // B fragment: lane l -> h = t*16 + (l&15), k = step*64 + s*32 + (l>>4)*8 + [0..7]
    const u16* Bp = BT + (long)l15 * NPED + kb + l4 * 8;

    float4 a[2][4];
    u16x8  bb[2][8];
    f32x4  acc[4] = {};

    auto load_a = [&](int buf, int step) {
        const float* p = Ap + step * BK;
        a[buf][0] = *(const float4*)(p);
        a[buf][1] = *(const float4*)(p + 4);
        a[buf][2] = *(const float4*)(p + 32);
        a[buf][3] = *(const float4*)(p + 36);
    };
    auto load_b = [&](int buf, int step) {
        const u16* p = Bp + step * BK;
        #pragma unroll
        for (int s = 0; s < 2; ++s)
            #pragma unroll
            for (int t = 0; t < 4; ++t)
                bb[buf][s * 4 + t] = *(const u16x8*)(p + (long)t * 16 * NPED + s * 32);
    };

    load_a(0, 0); load_b(0, 0);

    #pragma unroll
    for (int step = 0; step < NSTEPS; ++step) {
        const int cur = step & 1, nxt = cur ^ 1;
        if (step + 1 < NSTEPS) { load_a(nxt, step + 1); load_b(nxt, step + 1); }
        bf16x8 af0 = cvt8(a[cur][0], a[cur][1]);
        bf16x8 af1 = cvt8(a[cur][2], a[cur][3]);
        #pragma unroll
        for (int s = 0; s < 2; ++s) {
            const bf16x8 af = s ? af1 : af0;
            #pragma unroll
            for (int t = 0; t < 4; ++t) {
                bf16x8 bf = __builtin_bit_cast(bf16x8, bb[cur][s * 4 + t]);
                acc[t] = __builtin_amdgcn_mfma_f32_16x16x32_bf16(af, bf, acc[t], 0, 0, 0);
            }
        }
    }

    // Epilogue: C/D layout col = lane&15, row = (lane>>4)*4 + reg
    #pragma unroll
    for (int t = 0; t < 4; ++t) {
        #pragma unroll
        for (int r = 0; r < 4; ++r) {
            int row = rb * BM + w * 16 + l4 * 4 + r;
            int col = t * 16 + l15;
            atomicAdd(&out[row * HID + col], acc[t][r]);
        }
    }
}

extern "C" void kernel_launch(void* const* d_in, const int* in_sizes, int n_in,
                              void* d_out, int out_size, void* d_ws, size_t ws_size,
                              hipStream_t stream) {
    const float* A = (const float*)d_in[0];   // location_data [8192, 8192]
    const float* B = (const float*)d_in[1];   // motion_data   [8192, 64]
    float* out = (float*)d_out;               // [8192, 64]
    u16* BT = (u16*)d_ws;                     // 64*8192*2 = 1 MB

    hipMemsetAsync(d_out, 0, (size_t)out_size * sizeof(float), stream);
    transpose_b<<<dim3(NPED / 64), 256, 0, stream>>>(B, BT);

    dim3 grid(NPED / BM, KSPLIT);
    crowd_mm<<<grid, 256, 0, stream>>>(A, BT, out);
}

// Round 4
// 87.360 us; speedup vs baseline: 1.2499x; 1.2499x over previous
//
#include <hip/hip_runtime.h>
#include <hip/hip_bf16.h>

// out[8192,64] = L[8192,8192] (fp32) @ M[8192,64] (fp32)
// K1: BT[h][k] = (bf16)M[k][h]  (1 MB in d_ws, L2-resident)
// K2: A staged fp32 via global_load_lds(16B), double-buffered, XOR-swizzled
//     (pre-swizzled global source, swizzled ds_read). B fragment-direct from BT,
//     double-buffered in NAMED reg arrays (constant indices only).
//     Counted s_waitcnt vmcnt(12) — next tile's 12 loads stay in flight across
//     both barriers; vmcnt(0) only at the final step. Split-K=8, fp32 atomics.

#define NPED 8192
#define HID  64
#define BM   64
#define BK   64
#define KSPLIT 8
#define KRANGE (NPED / KSPLIT)   // 1024
#define NSTEPS (KRANGE / BK)     // 16

typedef __bf16 bf16x8 __attribute__((ext_vector_type(8)));
typedef float  f32x4  __attribute__((ext_vector_type(4)));
typedef unsigned short u16;
typedef u16 u16x8 __attribute__((ext_vector_type(8)));

__device__ __forceinline__ bf16x8 cvt8(float4 lo, float4 hi) {
    bf16x8 r;
    r[0] = (__bf16)lo.x; r[1] = (__bf16)lo.y; r[2] = (__bf16)lo.z; r[3] = (__bf16)lo.w;
    r[4] = (__bf16)hi.x; r[5] = (__bf16)hi.y; r[6] = (__bf16)hi.z; r[7] = (__bf16)hi.w;
    return r;
}

__device__ __forceinline__ void gl_lds16(const void* g, void* l) {
    __builtin_amdgcn_global_load_lds(
        (const __attribute__((address_space(1))) void*)g,
        (__attribute__((address_space(3))) void*)l, 16, 0, 0);
}

// ---- Kernel 1: B [8192,64] fp32 -> BT [64,8192] bf16 ----
__global__ __launch_bounds__(256)
void transpose_b(const float* __restrict__ B, u16* __restrict__ BT) {
    __shared__ u16 t[64][65];
    const int tid = threadIdx.x;
    const int kb  = blockIdx.x * 64;
    {
        const int r  = tid >> 2;
        const int c0 = (tid & 3) * 16;
        const float* p = B + (long)(kb + r) * HID + c0;
        #pragma unroll
        for (int j = 0; j < 16; j += 4) {
            float4 v = *(const float4*)(p + j);
            __bf16 b0 = (__bf16)v.x, b1 = (__bf16)v.y, b2 = (__bf16)v.z, b3 = (__bf16)v.w;
            t[c0 + j + 0][r] = __builtin_bit_cast(u16, b0);
            t[c0 + j + 1][r] = __builtin_bit_cast(u16, b1);
            t[c0 + j + 2][r] = __builtin_bit_cast(u16, b2);
            t[c0 + j + 3][r] = __builtin_bit_cast(u16, b3);
        }
    }
    __syncthreads();
    {
        const int h  = tid >> 2;
        const int kc = (tid & 3) * 16;
        u16x8 lo, hi;
        #pragma unroll
        for (int j = 0; j < 8; ++j) { lo[j] = t[h][kc + j]; hi[j] = t[h][kc + 8 + j]; }
        u16* q = BT + (long)h * NPED + kb + kc;
        *(u16x8*)(q)     = lo;
        *(u16x8*)(q + 8) = hi;
    }
}

// ---- Kernel 2: streaming MFMA ----
__global__ __launch_bounds__(256, 4)
void crowd_mm(const float* __restrict__ A, const u16* __restrict__ BT,
              float* __restrict__ out)
{
    __shared__ float lds0[BM * BK];   // 16 KB, row-XOR-swizzled fp32 A tile
    __shared__ float lds1[BM * BK];   // 16 KB

    const int tid  = threadIdx.x;
    const int lane = tid & 63;
    const int w    = tid >> 6;
    const int rb   = blockIdx.x;
    const int ks   = blockIdx.y;

    const int l15  = lane & 15;
    const int l4   = lane >> 4;
    const int kb16 = l15 * 16;        // staging: byte col within 256-B row

    // A tile base (bytes): block rows rb*64.., k-slice ks*1024 floats
    const char* Abase = (const char*)(A + (long)(rb * BM) * NPED + (long)ks * KRANGE);
    // B fragments: h = l15 (+16t), k = ks*1024 + step*64 + s*32 + l4*8 + [0..7]
    const u16* Bp = BT + (long)l15 * NPED + (long)ks * KRANGE + l4 * 8;

    u16x8 B0[8], B1[8];               // named double buffers, constant-indexed only
    f32x4 acc[4] = {};

    // stage step STEP of A into LBUF: 4 calls/wave, 1 KB each; lane l -> dest
    // byte (w*4+I)*1024 + l*16 = row (w*16+4I+(l>>4)), col (l&15)*16.
    // Source col pre-XOR'd so LDS[r][x] = A[r][x ^ ((r&7)<<4)].
#define STAGE(LBUF, STEP) do {                                                   \
    _Pragma("unroll")                                                            \
    for (int I = 0; I < 4; ++I) {                                                \
        const int row4 = w * 16 + I * 4 + (lane >> 4);                           \
        const char* src = Abase + (long)row4 * (NPED * 4)                        \
                        + (long)(STEP) * 256 + (kb16 ^ ((row4 & 7) << 4));       \
        gl_lds16(src, (char*)(LBUF) + (w * 4 + I) * 1024);                       \
    }                                                                            \
} while (0)

#define LOADB(DST, STEP) do {                                                    \
    _Pragma("unroll")                                                            \
    for (int t = 0; t < 4; ++t) {                                                \
        const u16* bp = Bp + (long)(STEP) * BK + (long)t * 16 * NPED;            \
        DST[t]     = *(const u16x8*)bp;                                          \
        DST[4 + t] = *(const u16x8*)(bp + 32);                                   \
    }                                                                            \
} while (0)

    // one K-step: counted vmcnt keeps younger loads in flight; two barriers
#define HALF(LBUF, BREG, VM) do {                                                \
    asm volatile("s_waitcnt vmcnt(" #VM ")" ::: "memory");                       \
    __builtin_amdgcn_s_barrier();                                                \
    const char* base_ = (const char*)(LBUF);                                     \
    const int row_   = w * 16 + l15;                                             \
    const int sw_    = (row_ & 7) << 4;                                          \
    const int rbyte_ = row_ * 256;                                               \
    float4 fa0 = *(const float4*)(base_ + rbyte_ + ((l4 * 32)            ^ sw_));\
    float4 fa1 = *(const float4*)(base_ + rbyte_ + ((l4 * 32 + 16)       ^ sw_));\
    float4 fa2 = *(const float4*)(base_ + rbyte_ + ((128 + l4 * 32)      ^ sw_));\
    float4 fa3 = *(const float4*)(base_ + rbyte_ + ((128 + l4 * 32 + 16) ^ sw_));\
    asm volatile("s_waitcnt lgkmcnt(0)" ::: "memory");                           \
    __builtin_amdgcn_s_barrier();                                                \
    bf16x8 af0 = cvt8(fa0, fa1);                                                 \
    bf16x8 af1 = cvt8(fa2, fa3);                                                 \
    _Pragma("unroll")                                                            \
    for (int t = 0; t < 4; ++t)                                                  \
        acc[t] = __builtin_amdgcn_mfma_f32_16x16x32_bf16(                        \
            af0, __builtin_bit_cast(bf16x8, BREG[t]), acc[t], 0, 0, 0);          \
    _Pragma("unroll")                                                            \
    for (int t = 0; t < 4; ++t)                                                  \
        acc[t] = __builtin_amdgcn_mfma_f32_16x16x32_bf16(                        \
            af1, __builtin_bit_cast(bf16x8, BREG[4 + t]), acc[t], 0, 0, 0);      \
} while (0)

    // Prologue: two tiles in flight (issue order: B(s) before A(s))
    LOADB(B0, 0);
    STAGE(lds0, 0);
    LOADB(B1, 1);
    STAGE(lds1, 1);

    for (int it = 0; it < 7; ++it) {
        const int s0 = 2 * it;
        HALF(lds0, B0, 12);            // consume step s0
        LOADB(B0, s0 + 2);
        STAGE(lds0, s0 + 2);
        HALF(lds1, B1, 12);            // consume step s0+1
        LOADB(B1, s0 + 3);
        STAGE(lds1, s0 + 3);
    }
    HALF(lds0, B0, 12);                // s = 14 (keeps step-15 loads in flight)
    HALF(lds1, B1, 0);                 // s = 15 (final drain)

    // Epilogue: C/D layout col = lane&15, row = (lane>>4)*4 + reg
    #pragma unroll
    for (int t = 0; t < 4; ++t) {
        #pragma unroll
        for (int r = 0; r < 4; ++r) {
            int row = rb * BM + w * 16 + l4 * 4 + r;
            int col = t * 16 + l15;
            atomicAdd(&out[row * HID + col], acc[t][r]);
        }
    }
#undef STAGE
#undef LOADB
#undef HALF
}

extern "C" void kernel_launch(void* const* d_in, const int* in_sizes, int n_in,
                              void* d_out, int out_size, void* d_ws, size_t ws_size,
                              hipStream_t stream) {
    const float* A = (const float*)d_in[0];   // location_data [8192, 8192]
    const float* B = (const float*)d_in[1];   // motion_data   [8192, 64]
    float* out = (float*)d_out;               // [8192, 64]
    u16* BT = (u16*)d_ws;                     // 64*8192*2 = 1 MB scratch

    hipMemsetAsync(d_out, 0, (size_t)out_size * sizeof(float), stream);
    transpose_b<<<dim3(NPED / 64), 256, 0, stream>>>(B, BT);

    dim3 grid(NPED / BM, KSPLIT);
    crowd_mm<<<grid, 256, 0, stream>>>(A, BT, out);
}